// Round 1
// 253.739 us; speedup vs baseline: 1.1385x; 1.1385x over previous
//
#include <hip/hip_runtime.h>
#include <hip/hip_bf16.h>

#define BSZ 4096
#define MAXLEN 200
#define EDIM 112
#define NW 8   // waves per bg_fused block (split-K factor)

typedef __attribute__((ext_vector_type(8))) short bf16x8;
typedef __attribute__((ext_vector_type(4))) float f32x4;

// f32 -> bf16 (RNE), bit-level
static __device__ __forceinline__ short f2bf(float f) {
    unsigned u = __float_as_uint(f);
    unsigned r = (u + 0x7fffu + ((u >> 16) & 1u)) >> 16;
    return (short)r;
}
static __device__ __forceinline__ float bf2f(short s) {
    return __uint_as_float(((unsigned)(unsigned short)s) << 16);
}
static __device__ __forceinline__ bf16x8 cvt8(float4 a, float4 b) {
    bf16x8 r;
    r[0] = f2bf(a.x); r[1] = f2bf(a.y); r[2] = f2bf(a.z); r[3] = f2bf(a.w);
    r[4] = f2bf(b.x); r[5] = f2bf(b.y); r[6] = f2bf(b.z); r[7] = f2bf(b.w);
    return r;
}
static __device__ __forceinline__ unsigned pack2(float a, float b) {
    return ((unsigned)f2bf(a) & 0xffffu) | ((unsigned)f2bf(b) << 16);
}

// Streaming f32 -> bf16; first `zgroups` 8-elem groups are zeros (PAD row).
__global__ __launch_bounds__(256) void f32_to_bf16(const float* __restrict__ src,
                                                   unsigned short* __restrict__ dst,
                                                   int ngroups, int zgroups) {
    int g = blockIdx.x * 256 + threadIdx.x;
    if (g >= ngroups) return;
    bf16x8 o;
    if (g < zgroups) {
        #pragma unroll
        for (int i = 0; i < 8; ++i) o[i] = 0;
    } else {
        const float* p = src + (size_t)(g - zgroups) * 8;
        float4 a = *(const float4*)p;
        float4 b = *(const float4*)(p + 4);
        o = cvt8(a, b);
    }
    *(bf16x8*)(dst + (size_t)g * 8) = o;
}

// bf16-table gather+mean-pool. One block per session; 4 waves x 4 rows/wave,
// 16 B/lane loads; Ebf row 0 is zeros (PAD).  Writes S and inits acc.
__global__ __launch_bounds__(256) void gather_pool_bf(const unsigned short* __restrict__ Ebf,
                                                      const int* __restrict__ items,
                                                      const float* __restrict__ slen,
                                                      float* __restrict__ S,
                                                      float* __restrict__ acc) {
    __shared__ float part[16][14][8];
    int wave = threadIdx.x >> 6;
    int lane = threadIdx.x & 63;
    int b = blockIdx.x;
    int rg = lane / 14;   // 0..3 for lanes 0..55
    int c  = lane % 14;
    const int* it = items + (size_t)b * MAXLEN + wave * 50;
    float a[8];
    #pragma unroll
    for (int e = 0; e < 8; ++e) a[e] = 0.f;
    if (lane < 56) {
        #pragma unroll
        for (int t = 0; t < 13; ++t) {
            int j = t * 4 + rg;
            int idx = 0;
            if (j < 50) idx = it[j];               // idx==0 -> zero row (PAD)
            bf16x8 v = *(const bf16x8*)(Ebf + (size_t)idx * EDIM + c * 8);
            #pragma unroll
            for (int e = 0; e < 8; ++e) a[e] += bf2f(v[e]);
        }
        #pragma unroll
        for (int e = 0; e < 8; ++e) part[wave * 4 + rg][c][e] = a[e];
    }
    __syncthreads();
    int tid = threadIdx.x;
    if (tid < EDIM) {
        int cc = tid >> 3, ee = tid & 7;
        float s = 0.f;
        #pragma unroll
        for (int g = 0; g < 16; ++g) s += part[g][cc][ee];
        s /= slen[b];
        S[(size_t)b * EDIM + tid]   = s;
        acc[(size_t)b * EDIM + tid] = s;
    }
}

// Load 8 consecutive f32 (if valid) -> bf16x8 fragment.
static __device__ __forceinline__ bf16x8 ldcvt(const float* p, bool valid) {
    if (valid) {
        float4 a = *(const float4*)(p);
        float4 b = *(const float4*)(p + 4);
        return cvt8(a, b);
    }
    bf16x8 z;
    #pragma unroll
    for (int i = 0; i < 8; ++i) z[i] = 0;
    return z;
}

// Layer-0 only: T1 = S @ W0^T -> Bsw fragment layout.  One wave per 16
// sessions, grid 256.  (The MODE-1 epilogue work now lives inside bg_fused.)
__global__ __launch_bounds__(64, 4) void fused_mid0(const float* __restrict__ Sin,
                                                    const float* __restrict__ W,
                                                    unsigned short* __restrict__ Bsw) {
    __shared__ unsigned short Ylds[16][136];  // bank-skewed rows
    int lane = threadIdx.x;
    int gw = blockIdx.x;          // 0..255
    int j0 = gw * 16;
    int nrow = lane & 15;
    int quad = lane >> 4;
    int ses = j0 + nrow;

    float4 v[7];
    const float4* p = (const float4*)(Sin + (size_t)ses * EDIM + quad * 28);
    #pragma unroll
    for (int i = 0; i < 7; ++i) v[i] = p[i];

    // bf16 Y tile to LDS (cols 112..127 zeroed for K-padding)
    #pragma unroll
    for (int i = 0; i < 7; ++i) {
        uint2 pk;
        pk.x = pack2(v[i].x, v[i].y);
        pk.y = pack2(v[i].z, v[i].w);
        *(uint2*)&Ylds[nrow][quad * 28 + i * 4] = pk;
    }
    *(uint2*)&Ylds[nrow][112 + quad * 4] = make_uint2(0u, 0u);
    __syncthreads();

    bf16x8 aF[4];
    #pragma unroll
    for (int k32 = 0; k32 < 4; ++k32)
        aF[k32] = *(bf16x8*)&Ylds[nrow][k32 * 32 + quad * 8];

    f32x4 acc[7];
    #pragma unroll
    for (int t = 0; t < 7; ++t) acc[t] = (f32x4){0.f, 0.f, 0.f, 0.f};
    #pragma unroll
    for (int t = 0; t < 7; ++t) {
        const float* wr = W + (size_t)(16 * t + nrow) * EDIM;
        #pragma unroll
        for (int k32 = 0; k32 < 4; ++k32) {
            bf16x8 bF = ldcvt(wr + k32 * 32 + quad * 8, (k32 < 3) || (quad < 2));
            acc[t] = __builtin_amdgcn_mfma_f32_16x16x32_bf16(aF[k32], bF, acc[t], 0, 0, 0);
        }
    }

    // scatter C into Bsw fragment layout
    int k32f = j0 >> 5;
    int qp = ((j0 >> 4) & 1) * 2 + (quad >> 1);
    int e0 = (quad & 1) * 4;
    #pragma unroll
    for (int t = 0; t < 7; ++t) {
        uint2 pk;
        pk.x = pack2(acc[t][0], acc[t][1]);
        pk.y = pack2(acc[t][2], acc[t][3]);
        *(uint2*)(Bsw + ((size_t)(k32f * 7 + t) * 64 + qp * 16 + nrow) * 8 + e0) = pk;
    }
}

// Fused per-layer kernel: Y = D .* (A @ T) over the FULL K in one block
// (8 waves split K, reduce in LDS -> no Yp partial round-trip), then the
// epilogue (acc += Y/||Y||  or  out = (acc + Y/||Y||)/4) and the next
// layer's B-operand T' = Y @ W^T (7 waves, 4 MFMA each) all in-block.
// grid 256 x 512 thr; one block per 16-row M-tile.
// AMODE 0: read f32 A, cvt in-register, side-write Asw.  AMODE 1: read Asw.
// LAST 1: write out, skip T'.
template <int AMODE, int LAST>
__global__ __launch_bounds__(512, 2) void bg_fused(const float* __restrict__ Af,
                                                   unsigned short* __restrict__ Asw,
                                                   const unsigned short* __restrict__ Bsw,
                                                   const float* __restrict__ Dm,
                                                   float* __restrict__ accb,
                                                   const float* __restrict__ W,
                                                   unsigned short* __restrict__ BswOut,
                                                   float* __restrict__ out) {
    __shared__ float part[NW][16][116];        // 59392 B, stride 116 -> 2-way max
    __shared__ unsigned short Ylds[16][136];   // 4352 B
    int tid = threadIdx.x;
    int w = tid >> 6;
    int lane = tid & 63;
    int nrow = lane & 15;
    int quad = lane >> 4;
    int mtile = blockIdx.x;

    // ---- K-chunk GEMM: wave w covers k32 in [16w, 16w+16) ----
    f32x4 acc[7];
    #pragma unroll
    for (int t = 0; t < 7; ++t) acc[t] = (f32x4){0.f, 0.f, 0.f, 0.f};

    auto LOADA = [&](int k32) -> bf16x8 {
        size_t afrag = ((size_t)(mtile * 128 + k32) * 64 + lane) * 8;
        if (AMODE == 0) {
            const float* p = Af + (size_t)(mtile * 16 + nrow) * 4096 + k32 * 32 + quad * 8;
            float4 a0 = *(const float4*)p;
            float4 a1 = *(const float4*)(p + 4);
            bf16x8 r = cvt8(a0, a1);
            *(bf16x8*)(Asw + afrag) = r;       // side output for layers 2-3
            return r;
        } else {
            return *(const bf16x8*)(Asw + afrag);
        }
    };

    int k32 = w * 16;
    bf16x8 aF = LOADA(k32);
    bf16x8 bF[7];
    {
        const unsigned short* bb = Bsw + ((size_t)k32 * 7 * 64 + lane) * 8;
        #pragma unroll
        for (int t = 0; t < 7; ++t) bF[t] = *(const bf16x8*)(bb + (size_t)t * 512);
    }
    #pragma unroll 1
    for (int ks = 0; ks < 15; ++ks) {
        bf16x8 aN = LOADA(k32 + 1);
        bf16x8 bN[7];
        const unsigned short* bb = Bsw + ((size_t)(k32 + 1) * 7 * 64 + lane) * 8;
        #pragma unroll
        for (int t = 0; t < 7; ++t) bN[t] = *(const bf16x8*)(bb + (size_t)t * 512);
        #pragma unroll
        for (int t = 0; t < 7; ++t)
            acc[t] = __builtin_amdgcn_mfma_f32_16x16x32_bf16(aF, bF[t], acc[t], 0, 0, 0);
        aF = aN;
        #pragma unroll
        for (int t = 0; t < 7; ++t) bF[t] = bN[t];
        ++k32;
    }
    #pragma unroll
    for (int t = 0; t < 7; ++t)
        acc[t] = __builtin_amdgcn_mfma_f32_16x16x32_bf16(aF, bF[t], acc[t], 0, 0, 0);

    // ---- partials to LDS: element (m=quad*4+r, n=16t+nrow) ----
    #pragma unroll
    for (int t = 0; t < 7; ++t)
        #pragma unroll
        for (int r = 0; r < 4; ++r)
            part[w][quad * 4 + r][16 * t + nrow] = acc[t][r];
    __syncthreads();

    // ---- reduce + epilogue: half-wave (32 lanes, 28 active) per row ----
    int half = lane >> 5;
    int cg = lane & 31;           // float4 column group; 28..31 are K-pad
    int row = 2 * w + half;       // 0..15
    int grow = mtile * 16 + row;
    int col = cg * 4;
    float4 v = make_float4(0.f, 0.f, 0.f, 0.f);
    if (cg < 28) {
        #pragma unroll
        for (int p = 0; p < NW; ++p) {
            float4 t = *(const float4*)&part[p][row][col];
            v.x += t.x; v.y += t.y; v.z += t.z; v.w += t.w;
        }
    }
    float d = Dm[(size_t)grow * (BSZ + 1)];   // D diagonal
    v.x *= d; v.y *= d; v.z *= d; v.w *= d;
    float ss = v.x * v.x + v.y * v.y + v.z * v.z + v.w * v.w;
    ss += __shfl_xor(ss, 1, 64);
    ss += __shfl_xor(ss, 2, 64);
    ss += __shfl_xor(ss, 4, 64);
    ss += __shfl_xor(ss, 8, 64);
    ss += __shfl_xor(ss, 16, 64);             // stays within the 32-lane half
    float rinv = 1.f / fmaxf(sqrtf(ss), 1e-12f);
    if (cg < 28) {
        if (LAST) {
            float4 a = *(const float4*)(accb + (size_t)grow * EDIM + col);
            float4 o;
            o.x = (a.x + v.x * rinv) * 0.25f;
            o.y = (a.y + v.y * rinv) * 0.25f;
            o.z = (a.z + v.z * rinv) * 0.25f;
            o.w = (a.w + v.w * rinv) * 0.25f;
            *(float4*)(out + (size_t)grow * EDIM + col) = o;
        } else {
            float4* pa = (float4*)(accb + (size_t)grow * EDIM + col);
            float4 a = *pa;
            a.x += v.x * rinv; a.y += v.y * rinv;
            a.z += v.z * rinv; a.w += v.w * rinv;
            *pa = a;
        }
    }

    if (!LAST) {
        // un-normalized (d-scaled) Y -> bf16 Ylds; cg>=28 writes zeros (K-pad)
        uint2 pk;
        pk.x = pack2(v.x, v.y);
        pk.y = pack2(v.z, v.w);
        *(uint2*)&Ylds[row][col] = pk;
        __syncthreads();

        // ---- T' = Y @ W^T: wave t (<7) does W-tile t: 4 MFMA ----
        if (w < 7) {
            int t = w;
            bf16x8 aF2[4];
            #pragma unroll
            for (int k = 0; k < 4; ++k)
                aF2[k] = *(bf16x8*)&Ylds[nrow][k * 32 + quad * 8];
            f32x4 c = (f32x4){0.f, 0.f, 0.f, 0.f};
            const float* wr = W + (size_t)(16 * t + nrow) * EDIM;
            #pragma unroll
            for (int k = 0; k < 4; ++k) {
                bf16x8 bW = ldcvt(wr + k * 32 + quad * 8, (k < 3) || (quad < 2));
                c = __builtin_amdgcn_mfma_f32_16x16x32_bf16(aF2[k], bW, c, 0, 0, 0);
            }
            int j0 = mtile * 16;
            int k32f = j0 >> 5;
            int qp = ((j0 >> 4) & 1) * 2 + (quad >> 1);
            int e0 = (quad & 1) * 4;
            uint2 ck;
            ck.x = pack2(c[0], c[1]);
            ck.y = pack2(c[2], c[3]);
            *(uint2*)(BswOut + ((size_t)(k32f * 7 + t) * 64 + qp * 16 + nrow) * 8 + e0) = ck;
        }
    }
}

extern "C" void kernel_launch(void* const* d_in, const int* in_sizes, int n_in,
                              void* d_out, int out_size, void* d_ws, size_t ws_size,
                              hipStream_t stream) {
    (void)in_sizes; (void)n_in; (void)out_size; (void)ws_size;
    const float* emb   = (const float*)d_in[0];
    const float* Dm    = (const float*)d_in[1];
    const float* A     = (const float*)d_in[2];
    const float* slen  = (const float*)d_in[3];
    const float* Ws    = (const float*)d_in[4];
    const int*   items = (const int*)d_in[5];
    float* out = (float*)d_out;

    // workspace layout (16B-aligned), ~61.5 MB total
    char* w = (char*)d_ws;
    float* Sa   = (float*)w;                                   // 1835008 B
    float* accb = Sa + BSZ * EDIM;                             // 1835008 B
    unsigned short* Bsw0 = (unsigned short*)(accb + BSZ * EDIM);  // 917504 B
    unsigned short* Bsw1 = Bsw0 + (size_t)128 * 7 * 64 * 8;       // 917504 B
    unsigned short* Ebf  = Bsw1 + (size_t)128 * 7 * 64 * 8;       // 22400224 B
    unsigned short* Asw  = Ebf + (size_t)100001 * EDIM;           // 33554432 B

    // 1. embedding table -> bf16 (zero PAD row prepended)
    f32_to_bf16<<<5470, 256, 0, stream>>>(emb, Ebf, 1400014, 14);
    // 2. gather + mean-pool -> S, acc
    gather_pool_bf<<<BSZ, 256, 0, stream>>>(Ebf, items, slen, Sa, accb);
    // 3. T1 = S @ W0^T
    fused_mid0<<<256, 64, 0, stream>>>(Sa, Ws, Bsw0);
    // 4-6. three fused layers (last writes out)
    bg_fused<0, 0><<<256, 512, 0, stream>>>(A, Asw, Bsw0, Dm, accb,
                                            Ws + (size_t)EDIM * EDIM, Bsw1, nullptr);
    bg_fused<1, 0><<<256, 512, 0, stream>>>(nullptr, Asw, Bsw1, Dm, accb,
                                            Ws + (size_t)2 * EDIM * EDIM, Bsw0, nullptr);
    bg_fused<1, 1><<<256, 512, 0, stream>>>(nullptr, Asw, Bsw0, Dm, accb,
                                            nullptr, nullptr, out);
}